// Round 8
// baseline (57.165 us; speedup 1.0000x reference)
//
#include <hip/hip_runtime.h>

// MacUnit via interleaved-pair bf16 LUT (one thread per d0, 2 outputs).
// Round-6 post-mortem: r5 and r6 (2x different VALU/LDS cost) both ran 43.9us
// -> memory-system bound, specifically latency-hiding: 8 loads in flight per
// thread x 16 waves = 32KB/CU, right at the cliff for 27 GB/s/CU.
// Round-7: ILP 16 (64KB/CU in flight) + nontemporal loads/stores (192MB of
// touch-once traffic stays out of L2; table stays resident).
// (r7 compile fix: nontemporal builtins need native vector types, not HIP
// float2 — use ext_vector_type(2).)

#define IC_   512
#define B_    32768
#define OC_   1024
#define N_    1024
#define LOG2E 1.4426950408889634f
#define LO_   (-7.0f)
#define HI_   ( 7.0f)
#define SSTR  1025         // u32 stride per channel subtable (=1 mod 32)

typedef float vf2 __attribute__((ext_vector_type(2)));

// ---------- exact per-element 4-step update (round-2 math, verified) --------
__device__ __forceinline__ float mac_step4(float d, float an, float bn) {
    constexpr float C1 = 31.0f / 30.0f;
#pragma unroll
    for (int s = 0; s < 4; ++s) {
        const float xp = fmaf(an, d, bn);               // -(a*d+b)*log2e
        const float e  = __builtin_amdgcn_exp2f(xp);    // 2^xp == exp(-x)
        const float sg = __builtin_amdgcn_rcpf(1.0f + e);
        const float sgf = __builtin_amdgcn_fractf(sg);  // ==sg; ==0 at fp32 sat
        const float r  = sgf * C1;                      // velo; ang in revs
        const float q  = r * 0.25f;
        const float fr = __builtin_amdgcn_fractf(r);
        const float sn = __builtin_amdgcn_sinf(fr);     // sin(2*pi*fr)
        const float cs = __builtin_amdgcn_cosf(fr);
        d = fmaf(q, fmaf(d, sn, cs), d);
    }
    return d;
}

__device__ __forceinline__ unsigned f2bf(float x) {     // RNE f32->bf16 bits
    const unsigned u = __float_as_uint(x);
    return (u + 0x7fffu + ((u >> 16) & 1u)) >> 16;
}

// ---------- build: pairtab[ch*N + i] = bf16(w0*F0) | bf16(w1*F1)<<16 --------
__global__ __launch_bounds__(256) void mac_build_pair(
    const float* __restrict__ alpha, const float* __restrict__ beta,
    const float* __restrict__ att, unsigned* __restrict__ pairtab, float h)
{
    const int gid = blockIdx.x * 256 + threadIdx.x;     // 512K threads
    const int ch  = gid >> 10;
    const int i   = gid & (N_ - 1);
    const float d0 = fmaf((float)i, h, LO_);
    const int p0 = 2 * ch, p1 = 2 * ch + 1;
    const float v0 = att[p0] * mac_step4(d0, alpha[p0] * -LOG2E, beta[p0] * -LOG2E);
    const float v1 = att[p1] * mac_step4(d0, alpha[p1] * -LOG2E, beta[p1] * -LOG2E);
    pairtab[gid] = f2bf(v0) | (f2bf(v1) << 16);
}

// ---------- stream: 256 WGs x 1024 thr. block = (cg: 32 data chans,
// chunk: 2048 rows). thread: ch = tid&31, rw = tid>>5; one d0 -> 2 outputs.
// 16-deep load pipeline; nt loads/stores. ------------------------------------
#define ILP 16
__global__ __launch_bounds__(1024) void mac_stream(
    const unsigned* __restrict__ pairtab, const float* __restrict__ data,
    float* __restrict__ out, float invh)
{
    extern __shared__ unsigned lds[];        // 32 * 1025 u32 = 131,200 B

    const int tid   = threadIdx.x;
    const int cg    = blockIdx.x >> 4;       // 0..15: group of 32 channels
    const int chunk = blockIdx.x & 15;       // 0..15: 2048 rows

    const int ch = tid & 31;
    const int rw = tid >> 5;                 // 0..31

    const float* dptr = data + ((size_t)chunk * 2048 + rw) * IC_
                             + (size_t)cg * 32 + ch;
    vf2*         optr = (vf2*)(out + ((size_t)chunk * 2048 + rw) * OC_
                             + (size_t)cg * 64 + 2 * ch);

    // prefetch iteration 0 (16 loads in flight) before staging barrier
    float pre[ILP];
#pragma unroll
    for (int u = 0; u < ILP; ++u)
        pre[u] = __builtin_nontemporal_load(dptr + (size_t)u * 32 * IC_);

    // stage 32 subtables (1024 u32 each) at stride 1025
    {
        const uint4* src = (const uint4*)(pairtab + (size_t)cg * 32 * N_);
#pragma unroll
        for (int k = tid; k < 32 * N_ / 4; k += 1024) {
            const uint4 v = src[k];
            unsigned* dst = lds + (k >> 8) * SSTR + (k & 255) * 4;
            dst[0] = v.x; dst[1] = v.y; dst[2] = v.z; dst[3] = v.w;
        }
    }
    __syncthreads();

    const unsigned* sub = lds + ch * SSTR;
    const float fN1 = (float)(N_ - 1);
    const float off = -LO_ * invh;

    for (int it = 0; it < 2048 / (32 * ILP); ++it) {   // 4 iters
        float d0v[ILP];
#pragma unroll
        for (int u = 0; u < ILP; ++u) d0v[u] = pre[u];
        if (it < 2048 / (32 * ILP) - 1) {
            dptr += (size_t)ILP * 32 * IC_;
#pragma unroll
            for (int u = 0; u < ILP; ++u)
                pre[u] = __builtin_nontemporal_load(dptr + (size_t)u * 32 * IC_);
        }
#pragma unroll
        for (int u = 0; u < ILP; ++u) {
            float t = fmaf(d0v[u], invh, off);
            t = fminf(fmaxf(t, 0.0f), fN1);          // v_med3 clamp
            int i = (int)t;                          // trunc==floor (t>=0)
            i = min(i, N_ - 2);
            const float frac = t - (float)i;
            const unsigned w0 = sub[i];              // ds_read2_b32 pair
            const unsigned w1 = sub[i + 1];
            const float vlo0 = __uint_as_float(w0 << 16);          // f0 lo
            const float vhi0 = __uint_as_float(w1 << 16);          // f0 hi
            const float vlo1 = __uint_as_float(w0 & 0xffff0000u);  // f1 lo
            const float vhi1 = __uint_as_float(w1 & 0xffff0000u);  // f1 hi
            vf2 o;
            o.x = fmaf(frac, vhi0 - vlo0, vlo0);
            o.y = fmaf(frac, vhi1 - vlo1, vlo1);
            __builtin_nontemporal_store(o, optr + (size_t)u * 32 * (OC_ / 2));
        }
        optr += (size_t)ILP * 32 * (OC_ / 2);
    }
}

// ---------- round-2 fallback (trans-pipe kernel, known-good) ----------------
#define BPT 4
__global__ __launch_bounds__(256) void mac_fallback(
    const float* __restrict__ data, const float* __restrict__ alpha,
    const float* __restrict__ beta, const float* __restrict__ att,
    float* __restrict__ out)
{
    const int t  = blockIdx.x * 256 + threadIdx.x;
    const int c  = t & (IC_ - 1);
    const int bb = (t >> 9) * BPT;

    const float2 a2 = *reinterpret_cast<const float2*>(alpha + 2 * c);
    const float2 b2 = *reinterpret_cast<const float2*>(beta  + 2 * c);
    const float2 w2 = *reinterpret_cast<const float2*>(att   + 2 * c);

    float d[BPT][2];
#pragma unroll
    for (int k = 0; k < BPT; ++k) {
        const float v = data[(size_t)(bb + k) * IC_ + c];
        d[k][0] = v; d[k][1] = v;
    }
    const float an[2] = {a2.x * -LOG2E, a2.y * -LOG2E};
    const float bn[2] = {b2.x * -LOG2E, b2.y * -LOG2E};
#pragma unroll
    for (int k = 0; k < BPT; ++k) {
        d[k][0] = mac_step4(d[k][0], an[0], bn[0]);
        d[k][1] = mac_step4(d[k][1], an[1], bn[1]);
    }
#pragma unroll
    for (int k = 0; k < BPT; ++k) {
        float2 o; o.x = w2.x * d[k][0]; o.y = w2.y * d[k][1];
        *reinterpret_cast<float2*>(out + (size_t)(bb + k) * OC_ + 2 * c) = o;
    }
}

extern "C" void kernel_launch(void* const* d_in, const int* in_sizes, int n_in,
                              void* d_out, int out_size, void* d_ws, size_t ws_size,
                              hipStream_t stream) {
    const float* data  = (const float*)d_in[0];
    const float* att   = (const float*)d_in[3];
    const float* alpha = (const float*)d_in[4];
    const float* beta  = (const float*)d_in[5];
    float* out = (float*)d_out;

    const size_t tab_bytes = (size_t)IC_ * N_ * 4;       // 2 MiB packed pairs
    const int    lds_bytes = 32 * SSTR * 4;              // 131,200 B

    const bool dyn_ok = hipFuncSetAttribute(
        reinterpret_cast<const void*>(mac_stream),
        hipFuncAttributeMaxDynamicSharedMemorySize, lds_bytes) == hipSuccess;

    if (ws_size >= tab_bytes && dyn_ok) {
        unsigned* pairtab = (unsigned*)d_ws;
        const float h = (HI_ - LO_) / (float)(N_ - 1);
        mac_build_pair<<<(IC_ * N_) / 256, 256, 0, stream>>>(
            alpha, beta, att, pairtab, h);
        mac_stream<<<256, 1024, lds_bytes, stream>>>(
            pairtab, data, out, 1.0f / h);
    } else {
        mac_fallback<<<(B_ / BPT) * IC_ / 256, 256, 0, stream>>>(
            data, alpha, beta, att, out);
    }
}

// Round 9
// 43.060 us; speedup vs baseline: 1.3276x; 1.3276x over previous
//
#include <hip/hip_runtime.h>

// MacUnit via interleaved-pair bf16 LUT (one thread per d0, 2 outputs).
// Round-8 post-mortem: nt stores defeated L2 write-combining (43.9 -> 57.2us
// with ILP16+nt). Round-9 deconfounds: EXACT r6 kernel, single change ILP
// 8 -> 16 (64KB/CU in flight vs the ~33KB needed at 27 GB/s/CU), no nt.

#define IC_   512
#define B_    32768
#define OC_   1024
#define N_    1024
#define LOG2E 1.4426950408889634f
#define LO_   (-7.0f)
#define HI_   ( 7.0f)
#define SSTR  1025         // u32 stride per channel subtable (=1 mod 32)

// ---------- exact per-element 4-step update (round-2 math, verified) --------
__device__ __forceinline__ float mac_step4(float d, float an, float bn) {
    constexpr float C1 = 31.0f / 30.0f;
#pragma unroll
    for (int s = 0; s < 4; ++s) {
        const float xp = fmaf(an, d, bn);               // -(a*d+b)*log2e
        const float e  = __builtin_amdgcn_exp2f(xp);    // 2^xp == exp(-x)
        const float sg = __builtin_amdgcn_rcpf(1.0f + e);
        const float sgf = __builtin_amdgcn_fractf(sg);  // ==sg; ==0 at fp32 sat
        const float r  = sgf * C1;                      // velo; ang in revs
        const float q  = r * 0.25f;
        const float fr = __builtin_amdgcn_fractf(r);
        const float sn = __builtin_amdgcn_sinf(fr);     // sin(2*pi*fr)
        const float cs = __builtin_amdgcn_cosf(fr);
        d = fmaf(q, fmaf(d, sn, cs), d);
    }
    return d;
}

__device__ __forceinline__ unsigned f2bf(float x) {     // RNE f32->bf16 bits
    const unsigned u = __float_as_uint(x);
    return (u + 0x7fffu + ((u >> 16) & 1u)) >> 16;
}

// ---------- build: pairtab[ch*N + i] = bf16(w0*F0) | bf16(w1*F1)<<16 --------
__global__ __launch_bounds__(256) void mac_build_pair(
    const float* __restrict__ alpha, const float* __restrict__ beta,
    const float* __restrict__ att, unsigned* __restrict__ pairtab, float h)
{
    const int gid = blockIdx.x * 256 + threadIdx.x;     // 512K threads
    const int ch  = gid >> 10;
    const int i   = gid & (N_ - 1);
    const float d0 = fmaf((float)i, h, LO_);
    const int p0 = 2 * ch, p1 = 2 * ch + 1;
    const float v0 = att[p0] * mac_step4(d0, alpha[p0] * -LOG2E, beta[p0] * -LOG2E);
    const float v1 = att[p1] * mac_step4(d0, alpha[p1] * -LOG2E, beta[p1] * -LOG2E);
    pairtab[gid] = f2bf(v0) | (f2bf(v1) << 16);
}

// ---------- stream: 256 WGs x 1024 thr. block = (cg: 32 data chans,
// chunk: 2048 rows). thread: ch = tid&31, rw = tid>>5; one d0 -> 2 outputs.
// 16-deep load pipeline, plain loads/stores. ---------------------------------
#define ILP 16
__global__ __launch_bounds__(1024) void mac_stream(
    const unsigned* __restrict__ pairtab, const float* __restrict__ data,
    float* __restrict__ out, float invh)
{
    extern __shared__ unsigned lds[];        // 32 * 1025 u32 = 131,200 B

    const int tid   = threadIdx.x;
    const int cg    = blockIdx.x >> 4;       // 0..15: group of 32 channels
    const int chunk = blockIdx.x & 15;       // 0..15: 2048 rows

    const int ch = tid & 31;
    const int rw = tid >> 5;                 // 0..31

    const float* dptr = data + ((size_t)chunk * 2048 + rw) * IC_
                             + (size_t)cg * 32 + ch;
    float2*      optr = (float2*)(out + ((size_t)chunk * 2048 + rw) * OC_
                             + (size_t)cg * 64 + 2 * ch);

    // prefetch iteration 0 (16 loads in flight) before staging barrier
    float pre[ILP];
#pragma unroll
    for (int u = 0; u < ILP; ++u) pre[u] = dptr[(size_t)u * 32 * IC_];

    // stage 32 subtables (1024 u32 each) at stride 1025
    {
        const uint4* src = (const uint4*)(pairtab + (size_t)cg * 32 * N_);
#pragma unroll
        for (int k = tid; k < 32 * N_ / 4; k += 1024) {
            const uint4 v = src[k];
            unsigned* dst = lds + (k >> 8) * SSTR + (k & 255) * 4;
            dst[0] = v.x; dst[1] = v.y; dst[2] = v.z; dst[3] = v.w;
        }
    }
    __syncthreads();

    const unsigned* sub = lds + ch * SSTR;
    const float fN1 = (float)(N_ - 1);
    const float off = -LO_ * invh;

    for (int it = 0; it < 2048 / (32 * ILP); ++it) {   // 4 iters
        float d0v[ILP];
#pragma unroll
        for (int u = 0; u < ILP; ++u) d0v[u] = pre[u];
        if (it < 2048 / (32 * ILP) - 1) {
            dptr += (size_t)ILP * 32 * IC_;
#pragma unroll
            for (int u = 0; u < ILP; ++u)
                pre[u] = dptr[(size_t)u * 32 * IC_];
        }
#pragma unroll
        for (int u = 0; u < ILP; ++u) {
            float t = fmaf(d0v[u], invh, off);
            t = fminf(fmaxf(t, 0.0f), fN1);          // v_med3 clamp
            int i = (int)t;                          // trunc==floor (t>=0)
            i = min(i, N_ - 2);
            const float frac = t - (float)i;
            const unsigned w0 = sub[i];              // ds_read2_b32 pair
            const unsigned w1 = sub[i + 1];
            const float vlo0 = __uint_as_float(w0 << 16);          // f0 lo
            const float vhi0 = __uint_as_float(w1 << 16);          // f0 hi
            const float vlo1 = __uint_as_float(w0 & 0xffff0000u);  // f1 lo
            const float vhi1 = __uint_as_float(w1 & 0xffff0000u);  // f1 hi
            float2 o;
            o.x = fmaf(frac, vhi0 - vlo0, vlo0);
            o.y = fmaf(frac, vhi1 - vlo1, vlo1);
            optr[(size_t)u * 32 * (OC_ / 2)] = o;
        }
        optr += (size_t)ILP * 32 * (OC_ / 2);
    }
}

// ---------- round-2 fallback (trans-pipe kernel, known-good) ----------------
#define BPT 4
__global__ __launch_bounds__(256) void mac_fallback(
    const float* __restrict__ data, const float* __restrict__ alpha,
    const float* __restrict__ beta, const float* __restrict__ att,
    float* __restrict__ out)
{
    const int t  = blockIdx.x * 256 + threadIdx.x;
    const int c  = t & (IC_ - 1);
    const int bb = (t >> 9) * BPT;

    const float2 a2 = *reinterpret_cast<const float2*>(alpha + 2 * c);
    const float2 b2 = *reinterpret_cast<const float2*>(beta  + 2 * c);
    const float2 w2 = *reinterpret_cast<const float2*>(att   + 2 * c);

    float d[BPT][2];
#pragma unroll
    for (int k = 0; k < BPT; ++k) {
        const float v = data[(size_t)(bb + k) * IC_ + c];
        d[k][0] = v; d[k][1] = v;
    }
    const float an[2] = {a2.x * -LOG2E, a2.y * -LOG2E};
    const float bn[2] = {b2.x * -LOG2E, b2.y * -LOG2E};
#pragma unroll
    for (int k = 0; k < BPT; ++k) {
        d[k][0] = mac_step4(d[k][0], an[0], bn[0]);
        d[k][1] = mac_step4(d[k][1], an[1], bn[1]);
    }
#pragma unroll
    for (int k = 0; k < BPT; ++k) {
        float2 o; o.x = w2.x * d[k][0]; o.y = w2.y * d[k][1];
        *reinterpret_cast<float2*>(out + (size_t)(bb + k) * OC_ + 2 * c) = o;
    }
}

extern "C" void kernel_launch(void* const* d_in, const int* in_sizes, int n_in,
                              void* d_out, int out_size, void* d_ws, size_t ws_size,
                              hipStream_t stream) {
    const float* data  = (const float*)d_in[0];
    const float* att   = (const float*)d_in[3];
    const float* alpha = (const float*)d_in[4];
    const float* beta  = (const float*)d_in[5];
    float* out = (float*)d_out;

    const size_t tab_bytes = (size_t)IC_ * N_ * 4;       // 2 MiB packed pairs
    const int    lds_bytes = 32 * SSTR * 4;              // 131,200 B

    const bool dyn_ok = hipFuncSetAttribute(
        reinterpret_cast<const void*>(mac_stream),
        hipFuncAttributeMaxDynamicSharedMemorySize, lds_bytes) == hipSuccess;

    if (ws_size >= tab_bytes && dyn_ok) {
        unsigned* pairtab = (unsigned*)d_ws;
        const float h = (HI_ - LO_) / (float)(N_ - 1);
        mac_build_pair<<<(IC_ * N_) / 256, 256, 0, stream>>>(
            alpha, beta, att, pairtab, h);
        mac_stream<<<256, 1024, lds_bytes, stream>>>(
            pairtab, data, out, 1.0f / h);
    } else {
        mac_fallback<<<(B_ / BPT) * IC_ / 256, 256, 0, stream>>>(
            data, alpha, beta, att, out);
    }
}

// Round 10
// 40.840 us; speedup vs baseline: 1.3997x; 1.0544x over previous
//
#include <hip/hip_runtime.h>

// MacUnit via interleaved-pair bf16 LUT (one thread per d0, 2 outputs).
// Round-9 post-mortem: ILP16 flat (43.9->43.1) -> latency-hiding NOT the
// limiter. Remaining suspect: DRAM page density — each block reads 128B per
// 2KB data row / writes 256B per 4KB out row, and the 16 blocks sharing a
// row-range were blockIdx stride-16 (same XCD, no temporal alignment).
// Round-10 (one line): cg = bid&15, chunk = bid>>4 — row-sharing blocks are
// now CONSECUTIVE bids: co-dispatched, lockstep through the same rows, their
// segments merge into full-page coverage at the memory controllers.

#define IC_   512
#define B_    32768
#define OC_   1024
#define N_    1024
#define LOG2E 1.4426950408889634f
#define LO_   (-7.0f)
#define HI_   ( 7.0f)
#define SSTR  1025         // u32 stride per channel subtable (=1 mod 32)

// ---------- exact per-element 4-step update (round-2 math, verified) --------
__device__ __forceinline__ float mac_step4(float d, float an, float bn) {
    constexpr float C1 = 31.0f / 30.0f;
#pragma unroll
    for (int s = 0; s < 4; ++s) {
        const float xp = fmaf(an, d, bn);               // -(a*d+b)*log2e
        const float e  = __builtin_amdgcn_exp2f(xp);    // 2^xp == exp(-x)
        const float sg = __builtin_amdgcn_rcpf(1.0f + e);
        const float sgf = __builtin_amdgcn_fractf(sg);  // ==sg; ==0 at fp32 sat
        const float r  = sgf * C1;                      // velo; ang in revs
        const float q  = r * 0.25f;
        const float fr = __builtin_amdgcn_fractf(r);
        const float sn = __builtin_amdgcn_sinf(fr);     // sin(2*pi*fr)
        const float cs = __builtin_amdgcn_cosf(fr);
        d = fmaf(q, fmaf(d, sn, cs), d);
    }
    return d;
}

__device__ __forceinline__ unsigned f2bf(float x) {     // RNE f32->bf16 bits
    const unsigned u = __float_as_uint(x);
    return (u + 0x7fffu + ((u >> 16) & 1u)) >> 16;
}

// ---------- build: pairtab[ch*N + i] = bf16(w0*F0) | bf16(w1*F1)<<16 --------
__global__ __launch_bounds__(256) void mac_build_pair(
    const float* __restrict__ alpha, const float* __restrict__ beta,
    const float* __restrict__ att, unsigned* __restrict__ pairtab, float h)
{
    const int gid = blockIdx.x * 256 + threadIdx.x;     // 512K threads
    const int ch  = gid >> 10;
    const int i   = gid & (N_ - 1);
    const float d0 = fmaf((float)i, h, LO_);
    const int p0 = 2 * ch, p1 = 2 * ch + 1;
    const float v0 = att[p0] * mac_step4(d0, alpha[p0] * -LOG2E, beta[p0] * -LOG2E);
    const float v1 = att[p1] * mac_step4(d0, alpha[p1] * -LOG2E, beta[p1] * -LOG2E);
    pairtab[gid] = f2bf(v0) | (f2bf(v1) << 16);
}

// ---------- stream: 256 WGs x 1024 thr. block = (cg: 32 data chans,
// chunk: 2048 rows). thread: ch = tid&31, rw = tid>>5; one d0 -> 2 outputs.
// 16-deep load pipeline, plain loads/stores. ---------------------------------
#define ILP 16
__global__ __launch_bounds__(1024) void mac_stream(
    const unsigned* __restrict__ pairtab, const float* __restrict__ data,
    float* __restrict__ out, float invh)
{
    extern __shared__ unsigned lds[];        // 32 * 1025 u32 = 131,200 B

    const int tid   = threadIdx.x;
    const int cg    = blockIdx.x & 15;       // 0..15: group of 32 channels
    const int chunk = blockIdx.x >> 4;       // 0..15: 2048 rows
    // ^ r10: row-sharing blocks are consecutive bids (temporal page merge)

    const int ch = tid & 31;
    const int rw = tid >> 5;                 // 0..31

    const float* dptr = data + ((size_t)chunk * 2048 + rw) * IC_
                             + (size_t)cg * 32 + ch;
    float2*      optr = (float2*)(out + ((size_t)chunk * 2048 + rw) * OC_
                             + (size_t)cg * 64 + 2 * ch);

    // prefetch iteration 0 (16 loads in flight) before staging barrier
    float pre[ILP];
#pragma unroll
    for (int u = 0; u < ILP; ++u) pre[u] = dptr[(size_t)u * 32 * IC_];

    // stage 32 subtables (1024 u32 each) at stride 1025
    {
        const uint4* src = (const uint4*)(pairtab + (size_t)cg * 32 * N_);
#pragma unroll
        for (int k = tid; k < 32 * N_ / 4; k += 1024) {
            const uint4 v = src[k];
            unsigned* dst = lds + (k >> 8) * SSTR + (k & 255) * 4;
            dst[0] = v.x; dst[1] = v.y; dst[2] = v.z; dst[3] = v.w;
        }
    }
    __syncthreads();

    const unsigned* sub = lds + ch * SSTR;
    const float fN1 = (float)(N_ - 1);
    const float off = -LO_ * invh;

    for (int it = 0; it < 2048 / (32 * ILP); ++it) {   // 4 iters
        float d0v[ILP];
#pragma unroll
        for (int u = 0; u < ILP; ++u) d0v[u] = pre[u];
        if (it < 2048 / (32 * ILP) - 1) {
            dptr += (size_t)ILP * 32 * IC_;
#pragma unroll
            for (int u = 0; u < ILP; ++u)
                pre[u] = dptr[(size_t)u * 32 * IC_];
        }
#pragma unroll
        for (int u = 0; u < ILP; ++u) {
            float t = fmaf(d0v[u], invh, off);
            t = fminf(fmaxf(t, 0.0f), fN1);          // v_med3 clamp
            int i = (int)t;                          // trunc==floor (t>=0)
            i = min(i, N_ - 2);
            const float frac = t - (float)i;
            const unsigned w0 = sub[i];              // ds_read2_b32 pair
            const unsigned w1 = sub[i + 1];
            const float vlo0 = __uint_as_float(w0 << 16);          // f0 lo
            const float vhi0 = __uint_as_float(w1 << 16);          // f0 hi
            const float vlo1 = __uint_as_float(w0 & 0xffff0000u);  // f1 lo
            const float vhi1 = __uint_as_float(w1 & 0xffff0000u);  // f1 hi
            float2 o;
            o.x = fmaf(frac, vhi0 - vlo0, vlo0);
            o.y = fmaf(frac, vhi1 - vlo1, vlo1);
            optr[(size_t)u * 32 * (OC_ / 2)] = o;
        }
        optr += (size_t)ILP * 32 * (OC_ / 2);
    }
}

// ---------- round-2 fallback (trans-pipe kernel, known-good) ----------------
#define BPT 4
__global__ __launch_bounds__(256) void mac_fallback(
    const float* __restrict__ data, const float* __restrict__ alpha,
    const float* __restrict__ beta, const float* __restrict__ att,
    float* __restrict__ out)
{
    const int t  = blockIdx.x * 256 + threadIdx.x;
    const int c  = t & (IC_ - 1);
    const int bb = (t >> 9) * BPT;

    const float2 a2 = *reinterpret_cast<const float2*>(alpha + 2 * c);
    const float2 b2 = *reinterpret_cast<const float2*>(beta  + 2 * c);
    const float2 w2 = *reinterpret_cast<const float2*>(att   + 2 * c);

    float d[BPT][2];
#pragma unroll
    for (int k = 0; k < BPT; ++k) {
        const float v = data[(size_t)(bb + k) * IC_ + c];
        d[k][0] = v; d[k][1] = v;
    }
    const float an[2] = {a2.x * -LOG2E, a2.y * -LOG2E};
    const float bn[2] = {b2.x * -LOG2E, b2.y * -LOG2E};
#pragma unroll
    for (int k = 0; k < BPT; ++k) {
        d[k][0] = mac_step4(d[k][0], an[0], bn[0]);
        d[k][1] = mac_step4(d[k][1], an[1], bn[1]);
    }
#pragma unroll
    for (int k = 0; k < BPT; ++k) {
        float2 o; o.x = w2.x * d[k][0]; o.y = w2.y * d[k][1];
        *reinterpret_cast<float2*>(out + (size_t)(bb + k) * OC_ + 2 * c) = o;
    }
}

extern "C" void kernel_launch(void* const* d_in, const int* in_sizes, int n_in,
                              void* d_out, int out_size, void* d_ws, size_t ws_size,
                              hipStream_t stream) {
    const float* data  = (const float*)d_in[0];
    const float* att   = (const float*)d_in[3];
    const float* alpha = (const float*)d_in[4];
    const float* beta  = (const float*)d_in[5];
    float* out = (float*)d_out;

    const size_t tab_bytes = (size_t)IC_ * N_ * 4;       // 2 MiB packed pairs
    const int    lds_bytes = 32 * SSTR * 4;              // 131,200 B

    const bool dyn_ok = hipFuncSetAttribute(
        reinterpret_cast<const void*>(mac_stream),
        hipFuncAttributeMaxDynamicSharedMemorySize, lds_bytes) == hipSuccess;

    if (ws_size >= tab_bytes && dyn_ok) {
        unsigned* pairtab = (unsigned*)d_ws;
        const float h = (HI_ - LO_) / (float)(N_ - 1);
        mac_build_pair<<<(IC_ * N_) / 256, 256, 0, stream>>>(
            alpha, beta, att, pairtab, h);
        mac_stream<<<256, 1024, lds_bytes, stream>>>(
            pairtab, data, out, 1.0f / h);
    } else {
        mac_fallback<<<(B_ / BPT) * IC_ / 256, 256, 0, stream>>>(
            data, alpha, beta, att, out);
    }
}

// Round 11
// 40.782 us; speedup vs baseline: 1.4017x; 1.0014x over previous
//
#include <hip/hip_runtime.h>

// MacUnit via interleaved-pair bf16 LUT (one thread per d0, 2 outputs).
// Round-10 post-mortem: consecutive-bid row-sharing gave -5% (page/locality
// density confirmed). Residual limit: LDS caps channels/block at 32 ->
// 128B per 2KB data row. Round-11: N=512, 64 channels/block (same 131KB LDS):
// each wave reads 256B of ONE row, each block covers 2x the row segment,
// 8 co-scheduled blocks tile a full row. PWL err x4 -> predicted absmax
// ~0.13-0.20 vs threshold 0.311.

#define IC_   512
#define B_    32768
#define OC_   1024
#define N_    512          // LUT entries per channel
#define LOG2E 1.4426950408889634f
#define LO_   (-7.0f)
#define HI_   ( 7.0f)
#define SSTR  513          // u32 stride per channel subtable (=1 mod 32)

// ---------- exact per-element 4-step update (round-2 math, verified) --------
__device__ __forceinline__ float mac_step4(float d, float an, float bn) {
    constexpr float C1 = 31.0f / 30.0f;
#pragma unroll
    for (int s = 0; s < 4; ++s) {
        const float xp = fmaf(an, d, bn);               // -(a*d+b)*log2e
        const float e  = __builtin_amdgcn_exp2f(xp);    // 2^xp == exp(-x)
        const float sg = __builtin_amdgcn_rcpf(1.0f + e);
        const float sgf = __builtin_amdgcn_fractf(sg);  // ==sg; ==0 at fp32 sat
        const float r  = sgf * C1;                      // velo; ang in revs
        const float q  = r * 0.25f;
        const float fr = __builtin_amdgcn_fractf(r);
        const float sn = __builtin_amdgcn_sinf(fr);     // sin(2*pi*fr)
        const float cs = __builtin_amdgcn_cosf(fr);
        d = fmaf(q, fmaf(d, sn, cs), d);
    }
    return d;
}

__device__ __forceinline__ unsigned f2bf(float x) {     // RNE f32->bf16 bits
    const unsigned u = __float_as_uint(x);
    return (u + 0x7fffu + ((u >> 16) & 1u)) >> 16;
}

// ---------- build: pairtab[ch*N + i] = bf16(w0*F0) | bf16(w1*F1)<<16 --------
__global__ __launch_bounds__(256) void mac_build_pair(
    const float* __restrict__ alpha, const float* __restrict__ beta,
    const float* __restrict__ att, unsigned* __restrict__ pairtab, float h)
{
    const int gid = blockIdx.x * 256 + threadIdx.x;     // 262,144 threads
    const int ch  = gid >> 9;
    const int i   = gid & (N_ - 1);
    const float d0 = fmaf((float)i, h, LO_);
    const int p0 = 2 * ch, p1 = 2 * ch + 1;
    const float v0 = att[p0] * mac_step4(d0, alpha[p0] * -LOG2E, beta[p0] * -LOG2E);
    const float v1 = att[p1] * mac_step4(d0, alpha[p1] * -LOG2E, beta[p1] * -LOG2E);
    pairtab[gid] = f2bf(v0) | (f2bf(v1) << 16);
}

// ---------- stream: 256 WGs x 1024 thr. block = (cg: 64 data chans,
// chunk: 1024 rows). thread: ch = tid&63, rw = tid>>6; one d0 -> 2 outputs.
// Wave = 1 row x 256B read, 512B write. Row-sharing blocks = consecutive
// bids (cg = bid&7). 16-deep load pipeline, plain loads/stores. -------------
#define ILP 16
__global__ __launch_bounds__(1024) void mac_stream(
    const unsigned* __restrict__ pairtab, const float* __restrict__ data,
    float* __restrict__ out, float invh)
{
    extern __shared__ unsigned lds[];        // 64 * 513 u32 = 131,328 B

    const int tid   = threadIdx.x;
    const int cg    = blockIdx.x & 7;        // 0..7: group of 64 channels
    const int chunk = blockIdx.x >> 3;       // 0..31: 1024 rows

    const int ch = tid & 63;
    const int rw = tid >> 6;                 // 0..15

    const float* dptr = data + ((size_t)chunk * 1024 + rw) * IC_
                             + (size_t)cg * 64 + ch;
    float2*      optr = (float2*)(out + ((size_t)chunk * 1024 + rw) * OC_
                             + (size_t)cg * 128 + 2 * ch);

    // prefetch iteration 0 (16 loads in flight) before staging barrier
    float pre[ILP];
#pragma unroll
    for (int u = 0; u < ILP; ++u) pre[u] = dptr[(size_t)u * 16 * IC_];

    // stage 64 subtables (512 u32 each) at stride 513
    {
        const uint4* src = (const uint4*)(pairtab + (size_t)cg * 64 * N_);
#pragma unroll
        for (int k = tid; k < 64 * N_ / 4; k += 1024) {   // 8192 uint4
            const uint4 v = src[k];
            unsigned* dst = lds + (k >> 7) * SSTR + (k & 127) * 4;
            dst[0] = v.x; dst[1] = v.y; dst[2] = v.z; dst[3] = v.w;
        }
    }
    __syncthreads();

    const unsigned* sub = lds + ch * SSTR;
    const float fN1 = (float)(N_ - 1);
    const float off = -LO_ * invh;

    for (int it = 0; it < 1024 / (16 * ILP); ++it) {   // 4 iters
        float d0v[ILP];
#pragma unroll
        for (int u = 0; u < ILP; ++u) d0v[u] = pre[u];
        if (it < 1024 / (16 * ILP) - 1) {
            dptr += (size_t)ILP * 16 * IC_;
#pragma unroll
            for (int u = 0; u < ILP; ++u)
                pre[u] = dptr[(size_t)u * 16 * IC_];
        }
#pragma unroll
        for (int u = 0; u < ILP; ++u) {
            float t = fmaf(d0v[u], invh, off);
            t = fminf(fmaxf(t, 0.0f), fN1);          // v_med3 clamp
            int i = (int)t;                          // trunc==floor (t>=0)
            i = min(i, N_ - 2);
            const float frac = t - (float)i;
            const unsigned w0 = sub[i];              // ds_read2_b32 pair
            const unsigned w1 = sub[i + 1];
            const float vlo0 = __uint_as_float(w0 << 16);          // f0 lo
            const float vhi0 = __uint_as_float(w1 << 16);          // f0 hi
            const float vlo1 = __uint_as_float(w0 & 0xffff0000u);  // f1 lo
            const float vhi1 = __uint_as_float(w1 & 0xffff0000u);  // f1 hi
            float2 o;
            o.x = fmaf(frac, vhi0 - vlo0, vlo0);
            o.y = fmaf(frac, vhi1 - vlo1, vlo1);
            optr[(size_t)u * 16 * (OC_ / 2)] = o;
        }
        optr += (size_t)ILP * 16 * (OC_ / 2);
    }
}

// ---------- round-2 fallback (trans-pipe kernel, known-good) ----------------
#define BPT 4
__global__ __launch_bounds__(256) void mac_fallback(
    const float* __restrict__ data, const float* __restrict__ alpha,
    const float* __restrict__ beta, const float* __restrict__ att,
    float* __restrict__ out)
{
    const int t  = blockIdx.x * 256 + threadIdx.x;
    const int c  = t & (IC_ - 1);
    const int bb = (t >> 9) * BPT;

    const float2 a2 = *reinterpret_cast<const float2*>(alpha + 2 * c);
    const float2 b2 = *reinterpret_cast<const float2*>(beta  + 2 * c);
    const float2 w2 = *reinterpret_cast<const float2*>(att   + 2 * c);

    float d[BPT][2];
#pragma unroll
    for (int k = 0; k < BPT; ++k) {
        const float v = data[(size_t)(bb + k) * IC_ + c];
        d[k][0] = v; d[k][1] = v;
    }
    const float an[2] = {a2.x * -LOG2E, a2.y * -LOG2E};
    const float bn[2] = {b2.x * -LOG2E, b2.y * -LOG2E};
#pragma unroll
    for (int k = 0; k < BPT; ++k) {
        d[k][0] = mac_step4(d[k][0], an[0], bn[0]);
        d[k][1] = mac_step4(d[k][1], an[1], bn[1]);
    }
#pragma unroll
    for (int k = 0; k < BPT; ++k) {
        float2 o; o.x = w2.x * d[k][0]; o.y = w2.y * d[k][1];
        *reinterpret_cast<float2*>(out + (size_t)(bb + k) * OC_ + 2 * c) = o;
    }
}

extern "C" void kernel_launch(void* const* d_in, const int* in_sizes, int n_in,
                              void* d_out, int out_size, void* d_ws, size_t ws_size,
                              hipStream_t stream) {
    const float* data  = (const float*)d_in[0];
    const float* att   = (const float*)d_in[3];
    const float* alpha = (const float*)d_in[4];
    const float* beta  = (const float*)d_in[5];
    float* out = (float*)d_out;

    const size_t tab_bytes = (size_t)IC_ * N_ * 4;       // 1 MiB packed pairs
    const int    lds_bytes = 64 * SSTR * 4;              // 131,328 B

    const bool dyn_ok = hipFuncSetAttribute(
        reinterpret_cast<const void*>(mac_stream),
        hipFuncAttributeMaxDynamicSharedMemorySize, lds_bytes) == hipSuccess;

    if (ws_size >= tab_bytes && dyn_ok) {
        unsigned* pairtab = (unsigned*)d_ws;
        const float h = (HI_ - LO_) / (float)(N_ - 1);
        mac_build_pair<<<(IC_ * N_) / 256, 256, 0, stream>>>(
            alpha, beta, att, pairtab, h);
        mac_stream<<<256, 1024, lds_bytes, stream>>>(
            pairtab, data, out, 1.0f / h);
    } else {
        mac_fallback<<<(B_ / BPT) * IC_ / 256, 256, 0, stream>>>(
            data, alpha, beta, att, out);
    }
}

// Round 12
// 39.971 us; speedup vs baseline: 1.4302x; 1.0203x over previous
//
#include <hip/hip_runtime.h>

// MacUnit via interleaved-pair bf16 LUT (one thread per d0, 2 outputs).
// Ledger: r8 nt-stores -13us (negative); r9 ILP16 null; r10 consecutive-bid
// row-sharing -5% (win); r11 2x row density null. Remaining lever: occupancy.
// r11 ran 1 WG/CU (131KB LDS) = 16 waves. Round-12: 32 ch/block, N=512 ->
// LDS 65,664B -> 2 WGs/CU = 32 waves/CU (2x TLP; independent wave streams
// overlap store-drain + load-issue in a way register ILP cannot).

#define IC_   512
#define B_    32768
#define OC_   1024
#define N_    512          // LUT entries per channel
#define LOG2E 1.4426950408889634f
#define LO_   (-7.0f)
#define HI_   ( 7.0f)
#define SSTR  513          // u32 stride per channel subtable (=1 mod 32)

// ---------- exact per-element 4-step update (round-2 math, verified) --------
__device__ __forceinline__ float mac_step4(float d, float an, float bn) {
    constexpr float C1 = 31.0f / 30.0f;
#pragma unroll
    for (int s = 0; s < 4; ++s) {
        const float xp = fmaf(an, d, bn);               // -(a*d+b)*log2e
        const float e  = __builtin_amdgcn_exp2f(xp);    // 2^xp == exp(-x)
        const float sg = __builtin_amdgcn_rcpf(1.0f + e);
        const float sgf = __builtin_amdgcn_fractf(sg);  // ==sg; ==0 at fp32 sat
        const float r  = sgf * C1;                      // velo; ang in revs
        const float q  = r * 0.25f;
        const float fr = __builtin_amdgcn_fractf(r);
        const float sn = __builtin_amdgcn_sinf(fr);     // sin(2*pi*fr)
        const float cs = __builtin_amdgcn_cosf(fr);
        d = fmaf(q, fmaf(d, sn, cs), d);
    }
    return d;
}

__device__ __forceinline__ unsigned f2bf(float x) {     // RNE f32->bf16 bits
    const unsigned u = __float_as_uint(x);
    return (u + 0x7fffu + ((u >> 16) & 1u)) >> 16;
}

// ---------- build: pairtab[ch*N + i] = bf16(w0*F0) | bf16(w1*F1)<<16 --------
__global__ __launch_bounds__(256) void mac_build_pair(
    const float* __restrict__ alpha, const float* __restrict__ beta,
    const float* __restrict__ att, unsigned* __restrict__ pairtab, float h)
{
    const int gid = blockIdx.x * 256 + threadIdx.x;     // 262,144 threads
    const int ch  = gid >> 9;
    const int i   = gid & (N_ - 1);
    const float d0 = fmaf((float)i, h, LO_);
    const int p0 = 2 * ch, p1 = 2 * ch + 1;
    const float v0 = att[p0] * mac_step4(d0, alpha[p0] * -LOG2E, beta[p0] * -LOG2E);
    const float v1 = att[p1] * mac_step4(d0, alpha[p1] * -LOG2E, beta[p1] * -LOG2E);
    pairtab[gid] = f2bf(v0) | (f2bf(v1) << 16);
}

// ---------- stream: 512 WGs x 1024 thr (2 WGs/CU). block = (cg: 32 chans,
// chunk: 1024 rows). thread: ch = tid&31, rw = tid>>5; one d0 -> 2 outputs.
// Row-sharing blocks = consecutive bids (cg = bid&15). ILP 8. ---------------
#define ILP 8
__global__ __launch_bounds__(1024) void mac_stream(
    const unsigned* __restrict__ pairtab, const float* __restrict__ data,
    float* __restrict__ out, float invh)
{
    extern __shared__ unsigned lds[];        // 32 * 513 u32 = 65,664 B

    const int tid   = threadIdx.x;
    const int cg    = blockIdx.x & 15;       // 0..15: group of 32 channels
    const int chunk = blockIdx.x >> 4;       // 0..31: 1024 rows

    const int ch = tid & 31;
    const int rw = tid >> 5;                 // 0..31

    const float* dptr = data + ((size_t)chunk * 1024 + rw) * IC_
                             + (size_t)cg * 32 + ch;
    float2*      optr = (float2*)(out + ((size_t)chunk * 1024 + rw) * OC_
                             + (size_t)cg * 64 + 2 * ch);

    // prefetch iteration 0 before staging barrier
    float pre[ILP];
#pragma unroll
    for (int u = 0; u < ILP; ++u) pre[u] = dptr[(size_t)u * 32 * IC_];

    // stage 32 subtables (512 u32 each) at stride 513
    {
        const uint4* src = (const uint4*)(pairtab + (size_t)cg * 32 * N_);
#pragma unroll
        for (int k = tid; k < 32 * N_ / 4; k += 1024) {   // 4096 uint4
            const uint4 v = src[k];
            unsigned* dst = lds + (k >> 7) * SSTR + (k & 127) * 4;
            dst[0] = v.x; dst[1] = v.y; dst[2] = v.z; dst[3] = v.w;
        }
    }
    __syncthreads();

    const unsigned* sub = lds + ch * SSTR;
    const float fN1 = (float)(N_ - 1);
    const float off = -LO_ * invh;

    for (int it = 0; it < 1024 / (32 * ILP); ++it) {   // 4 iters
        float d0v[ILP];
#pragma unroll
        for (int u = 0; u < ILP; ++u) d0v[u] = pre[u];
        if (it < 1024 / (32 * ILP) - 1) {
            dptr += (size_t)ILP * 32 * IC_;
#pragma unroll
            for (int u = 0; u < ILP; ++u)
                pre[u] = dptr[(size_t)u * 32 * IC_];
        }
#pragma unroll
        for (int u = 0; u < ILP; ++u) {
            float t = fmaf(d0v[u], invh, off);
            t = fminf(fmaxf(t, 0.0f), fN1);          // v_med3 clamp
            int i = (int)t;                          // trunc==floor (t>=0)
            i = min(i, N_ - 2);
            const float frac = t - (float)i;
            const unsigned w0 = sub[i];              // ds_read2_b32 pair
            const unsigned w1 = sub[i + 1];
            const float vlo0 = __uint_as_float(w0 << 16);          // f0 lo
            const float vhi0 = __uint_as_float(w1 << 16);          // f0 hi
            const float vlo1 = __uint_as_float(w0 & 0xffff0000u);  // f1 lo
            const float vhi1 = __uint_as_float(w1 & 0xffff0000u);  // f1 hi
            float2 o;
            o.x = fmaf(frac, vhi0 - vlo0, vlo0);
            o.y = fmaf(frac, vhi1 - vlo1, vlo1);
            optr[(size_t)u * 32 * (OC_ / 2)] = o;
        }
        optr += (size_t)ILP * 32 * (OC_ / 2);
    }
}

// ---------- round-2 fallback (trans-pipe kernel, known-good) ----------------
#define BPT 4
__global__ __launch_bounds__(256) void mac_fallback(
    const float* __restrict__ data, const float* __restrict__ alpha,
    const float* __restrict__ beta, const float* __restrict__ att,
    float* __restrict__ out)
{
    const int t  = blockIdx.x * 256 + threadIdx.x;
    const int c  = t & (IC_ - 1);
    const int bb = (t >> 9) * BPT;

    const float2 a2 = *reinterpret_cast<const float2*>(alpha + 2 * c);
    const float2 b2 = *reinterpret_cast<const float2*>(beta  + 2 * c);
    const float2 w2 = *reinterpret_cast<const float2*>(att   + 2 * c);

    float d[BPT][2];
#pragma unroll
    for (int k = 0; k < BPT; ++k) {
        const float v = data[(size_t)(bb + k) * IC_ + c];
        d[k][0] = v; d[k][1] = v;
    }
    const float an[2] = {a2.x * -LOG2E, a2.y * -LOG2E};
    const float bn[2] = {b2.x * -LOG2E, b2.y * -LOG2E};
#pragma unroll
    for (int k = 0; k < BPT; ++k) {
        d[k][0] = mac_step4(d[k][0], an[0], bn[0]);
        d[k][1] = mac_step4(d[k][1], an[1], bn[1]);
    }
#pragma unroll
    for (int k = 0; k < BPT; ++k) {
        float2 o; o.x = w2.x * d[k][0]; o.y = w2.y * d[k][1];
        *reinterpret_cast<float2*>(out + (size_t)(bb + k) * OC_ + 2 * c) = o;
    }
}

extern "C" void kernel_launch(void* const* d_in, const int* in_sizes, int n_in,
                              void* d_out, int out_size, void* d_ws, size_t ws_size,
                              hipStream_t stream) {
    const float* data  = (const float*)d_in[0];
    const float* att   = (const float*)d_in[3];
    const float* alpha = (const float*)d_in[4];
    const float* beta  = (const float*)d_in[5];
    float* out = (float*)d_out;

    const size_t tab_bytes = (size_t)IC_ * N_ * 4;       // 1 MiB packed pairs
    const int    lds_bytes = 32 * SSTR * 4;              // 65,664 B

    const bool dyn_ok = hipFuncSetAttribute(
        reinterpret_cast<const void*>(mac_stream),
        hipFuncAttributeMaxDynamicSharedMemorySize, lds_bytes) == hipSuccess;

    if (ws_size >= tab_bytes && dyn_ok) {
        unsigned* pairtab = (unsigned*)d_ws;
        const float h = (HI_ - LO_) / (float)(N_ - 1);
        mac_build_pair<<<(IC_ * N_) / 256, 256, 0, stream>>>(
            alpha, beta, att, pairtab, h);
        mac_stream<<<512, 1024, lds_bytes, stream>>>(
            pairtab, data, out, 1.0f / h);
    } else {
        mac_fallback<<<(B_ / BPT) * IC_ / 256, 256, 0, stream>>>(
            data, alpha, beta, att, out);
    }
}